// Round 1
// baseline (194.861 us; speedup 1.0000x reference)
//
#include <hip/hip_runtime.h>
#include <stdint.h>

#define NB 4
#define NN 512
#define NC 64
#define NH 128
#define NCO 64
#define T_THRESH 10
#define MAXM 96

// mask dtype decode: int32 (w0==1), float32 (w0==0x3f800000), else packed bytes.
// mask[0] is guaranteed true for this problem (node 0 < 480).
__device__ inline bool read_mask(const void* mp, int idx) {
    const int* ip = (const int*)mp;
    int w0 = ip[0];
    if (w0 == 1) return ip[idx] != 0;
    if (w0 == 0x3f800000) return ((const float*)mp)[idx] != 0.0f;
    return ((const unsigned char*)mp)[idx] != 0;
}

// One wave (64 lanes) per row (b,i). Computes the "removed" half-matrix row as
// 8x u64 bitmasks (bit j of word k = column k*64+j removed by row i's dilation).
__global__ void dilate_kernel(const float* __restrict__ adj,
                              const void* __restrict__ maskp,
                              uint64_t* __restrict__ removed) {
    int wave = (blockIdx.x * blockDim.x + threadIdx.x) >> 6;
    int lane = threadIdx.x & 63;
    if (wave >= NB * NN) return;
    int i = wave & (NN - 1);
    const float* arow = adj + (size_t)wave * NN;

    uint64_t ball[8];
    int m = 0;
    #pragma unroll
    for (int k = 0; k < 8; ++k) {
        int j = k * 64 + lane;
        bool f = (j != i) && (arow[j] > 0.0f);
        uint64_t bl = __ballot(f);
        ball[k] = bl;
        m += __popcll(bl);
    }
    int skip = (m > T_THRESH) ? ((m + 1) >> 1) : 1;  // ceil(m/2), K_DIL=2
    bool dodil = (skip > 1) && read_mask(maskp, wave);

    int prefix = 0;
    #pragma unroll
    for (int k = 0; k < 8; ++k) {
        uint64_t bl = ball[k];
        int rank = prefix + __popcll(bl & ((1ull << lane) - 1ull));  // 0-based pos among neighbors
        bool f = (bl >> lane) & 1ull;
        bool rm = f && dodil && (((rank + 1) % skip) == 0);
        uint64_t rb = __ballot(rm);
        if (lane == 0) removed[(size_t)wave * 8 + k] = rb;
        prefix += __popcll(bl);
    }
}

// One 128-thread block per row (b,i): valid list -> LDS value stage ->
// per-channel rank-selection quantiles -> fused GIN MLP -> masked store.
__global__ void agg_mlp_kernel(const float* __restrict__ x,
                               const float* __restrict__ adj,
                               const void* __restrict__ maskp,
                               const float* __restrict__ W1,
                               const float* __restrict__ b1,
                               const float* __restrict__ W2,
                               const float* __restrict__ b2,
                               const uint64_t* __restrict__ removed,
                               float* __restrict__ out) {
    int row = blockIdx.x;  // b*NN + i
    int b = row >> 9;
    int i = row & (NN - 1);
    int tid = threadIdx.x;

    float* outp = out + (size_t)row * NCO;
    if (!read_mask(maskp, row)) {   // block-uniform early exit; must write zeros
        if (tid < NCO) outp[tid] = 0.0f;
        return;
    }

    __shared__ int s_idx[NN];
    __shared__ int s_cnt;
    __shared__ float s_vals[MAXM * NC];
    __shared__ float s_out[NC];
    __shared__ float s_h[NH];

    if (tid == 0) s_cnt = 0;
    __syncthreads();

    const float* arow = adj + (size_t)row * NN;
    const uint64_t* rem_i = removed + (size_t)row * 8;
    for (int j = tid; j < NN; j += blockDim.x) {
        bool valid;
        if (j == i) {
            valid = true;  // self-loop, never removed
        } else {
            valid = (arow[j] > 0.0f);
            if (valid) {
                bool rij = (rem_i[j >> 6] >> (j & 63)) & 1ull;
                bool rji = (removed[((size_t)(b * NN + j)) * 8 + (i >> 6)] >> (i & 63)) & 1ull;
                valid = !(rij || rji);
            }
        }
        if (valid) {
            int p = atomicAdd(&s_cnt, 1);
            s_idx[p] = j;
        }
    }
    __syncthreads();
    int m = s_cnt;  // >= 1 always (self-loop)

    bool use_lds = (m <= MAXM);
    if (use_lds) {
        for (int t = tid; t < m * NC; t += blockDim.x) {
            int j = t >> 6;
            int c = t & 63;
            s_vals[t] = x[((size_t)(b * NN + s_idx[j])) * NC + c];
        }
    }
    __syncthreads();

    if (tid < NC) {
        int c = tid;
        float mf = (float)m;
        const float taus[3] = {0.25f, 0.5f, 0.75f};
        const float wts[3]  = {0.25f, 0.5f, 0.25f};
        int tlo[3], thi[3];
        float tfrac[3];
        #pragma unroll
        for (int t = 0; t < 3; ++t) {
            float pos = taus[t] * (mf - 1.0f);
            if (pos < 0.0f) pos = 0.0f;
            float fl = floorf(pos);
            tlo[t] = (int)fl;
            thi[t] = (int)ceilf(pos);
            tfrac[t] = pos - fl;
        }
        float qv[6];
        const float* xb = x + (size_t)b * NN * NC;
        for (int j1 = 0; j1 < m; ++j1) {
            float v1 = use_lds ? s_vals[j1 * NC + c]
                               : xb[(size_t)s_idx[j1] * NC + c];
            int r = 0;
            if (use_lds) {
                for (int j2 = 0; j2 < m; ++j2) {
                    float v2 = s_vals[j2 * NC + c];
                    r += (v2 < v1) || (v2 == v1 && j2 < j1);
                }
            } else {
                for (int j2 = 0; j2 < m; ++j2) {
                    float v2 = xb[(size_t)s_idx[j2] * NC + c];
                    r += (v2 < v1) || (v2 == v1 && j2 < j1);
                }
            }
            #pragma unroll
            for (int t = 0; t < 3; ++t) {
                if (r == tlo[t]) qv[2 * t] = v1;
                if (r == thi[t]) qv[2 * t + 1] = v1;
            }
        }
        float agg = 0.0f;
        #pragma unroll
        for (int t = 0; t < 3; ++t) {
            float q = qv[2 * t] * (1.0f - tfrac[t]) + qv[2 * t + 1] * tfrac[t];
            agg += wts[t] * q;
        }
        s_out[c] = x[(size_t)row * NC + c] + agg;  // (1+eps)*x + agg, eps=0
    }
    __syncthreads();

    {   // h = relu(out @ W1 + b1), one k per thread (H=128 == blockDim)
        int k = tid;
        float acc = b1[k];
        #pragma unroll
        for (int cc = 0; cc < NC; ++cc)
            acc += s_out[cc] * W1[cc * NH + k];
        s_h[k] = acc > 0.0f ? acc : 0.0f;
    }
    __syncthreads();

    if (tid < NCO) {   // y = h @ W2 + b2 (mask known true here)
        int o = tid;
        float acc = b2[o];
        #pragma unroll
        for (int k = 0; k < NH; ++k)
            acc += s_h[k] * W2[k * NCO + o];
        outp[o] = acc;
    }
}

extern "C" void kernel_launch(void* const* d_in, const int* in_sizes, int n_in,
                              void* d_out, int out_size, void* d_ws, size_t ws_size,
                              hipStream_t stream) {
    const float* x   = (const float*)d_in[0];
    const float* adj = (const float*)d_in[1];
    const void* mask = d_in[2];
    const float* W1  = (const float*)d_in[3];
    const float* b1  = (const float*)d_in[4];
    const float* W2  = (const float*)d_in[5];
    const float* b2  = (const float*)d_in[6];
    float* out = (float*)d_out;
    uint64_t* removed = (uint64_t*)d_ws;  // NB*NN*8 u64 = 128 KB

    dilate_kernel<<<(NB * NN) / 4, 256, 0, stream>>>(adj, mask, removed);
    agg_mlp_kernel<<<NB * NN, 128, 0, stream>>>(x, adj, mask, W1, b1, W2, b2,
                                                removed, out);
}

// Round 2
// 150.430 us; speedup vs baseline: 1.2954x; 1.2954x over previous
//
#include <hip/hip_runtime.h>
#include <stdint.h>

#define NB 4
#define NN 512
#define NC 64
#define NH 128
#define NCO 64
#define MAXM 64          // fast-path cap on valid-neighbor count (realistic max ~55)
#define STR 17           // float4 row stride: 16 data + 1 pad (bank spread)

// mask dtype decode: int32 (w0==1), float32 (w0==0x3f800000), else packed bytes.
__device__ inline bool read_mask(const void* mp, int idx) {
    const int* ip = (const int*)mp;
    int w0 = ip[0];
    if (w0 == 1) return ip[idx] != 0;
    if (w0 == 0x3f800000) return ((const float*)mp)[idx] != 0.0f;
    return ((const unsigned char*)mp)[idx] != 0;
}

// One 256-thread block per row (b,i). Fuses dilation (on-the-fly symmetric
// removal via neighbor-row ballots), weighted-quantile aggregation
// (transposed LDS + float4 rank counting), and the GIN MLP.
__global__ __launch_bounds__(256) void fused_kernel(
        const float* __restrict__ x,
        const float* __restrict__ adj,
        const void* __restrict__ maskp,
        const float* __restrict__ W1,
        const float* __restrict__ b1,
        const float* __restrict__ W2,
        const float* __restrict__ b2,
        float* __restrict__ out)
{
    int row = blockIdx.x;            // b*NN + i
    int b = row >> 9, i = row & (NN - 1);
    int tid = threadIdx.x, lane = tid & 63, wv = tid >> 6;
    float* outp = out + (size_t)row * NCO;

    if (!read_mask(maskp, row)) {    // masked row: explicit zeros (out is poisoned)
        if (tid < NCO) outp[tid] = 0.0f;
        return;
    }

    __shared__ uint64_t s_nb[8];         // row i's neighbor bits (w/o self)
    __shared__ int s_idx[NN];            // valid neighbor list (unordered)
    __shared__ int s_cnt;
    __shared__ float4 s_q4[NC * STR];    // transposed values: channel-major
    __shared__ float s_qv[NC * 8];       // 6 quantile candidate slots per channel
    __shared__ float s_out[NC];
    __shared__ float s_h[NH];

    // ---- P1: ballot-scan row i -> neighbor bitmask (4 waves x 2 chunks) ----
    const float* arow = adj + (size_t)row * NN;
    for (int k = wv * 2; k < wv * 2 + 2; ++k) {
        int j = k * 64 + lane;
        bool f = (j != i) && (arow[j] > 0.0f);
        uint64_t bl = __ballot(f);
        if (lane == 0) s_nb[k] = bl;
    }
    if (tid == 0) s_cnt = 0;
    __syncthreads();

    int pfx[8]; int mpre = 0;
    #pragma unroll
    for (int k = 0; k < 8; ++k) { pfx[k] = mpre; mpre += __popcll(s_nb[k]); }
    int skip_i = (mpre > 10) ? ((mpre + 1) >> 1) : 1;   // ceil(m/2), K_DIL=2
    bool dodil_i = (skip_i > 1);                        // row mask known true

    if (tid == 0) { int p = atomicAdd(&s_cnt, 1); s_idx[p] = i; }  // self-loop

    // ---- P2: per neighbor j, decide removal (i->j from bits; j->i by rescanning
    // row j with a wave-wide ballot). Wave wv owns chunks 2wv, 2wv+1. ----
    int ic = i >> 6, ibit = i & 63;
    for (int k = wv * 2; k < wv * 2 + 2; ++k) {
        uint64_t bits = s_nb[k];
        while (bits) {
            int bj = __builtin_ctzll(bits);
            bits &= bits - 1;
            int j = k * 64 + bj;
            int rank_ij = pfx[k] + __popcll(s_nb[k] & ((1ull << bj) - 1ull));
            bool rem = dodil_i && (((rank_ij + 1) % skip_i) == 0);
            if (!rem) {
                const float* arj = adj + ((size_t)(b * NN + j)) * NN;
                int mj = 0, rank_ji = 0;
                #pragma unroll
                for (int kk = 0; kk < 8; ++kk) {
                    int j2 = kk * 64 + lane;
                    bool f = (j2 != j) && (arj[j2] > 0.0f);
                    uint64_t bl = __ballot(f);
                    mj += __popcll(bl);
                    if (kk < ic) rank_ji += __popcll(bl);
                    else if (kk == ic) rank_ji += __popcll(bl & ((1ull << ibit) - 1ull));
                }
                int skip_j = (mj > 10) ? ((mj + 1) >> 1) : 1;
                if (skip_j > 1 && read_mask(maskp, b * NN + j))
                    rem = (((rank_ji + 1) % skip_j) == 0);
            }
            if (!rem && lane == 0) {
                int p = atomicAdd(&s_cnt, 1);
                s_idx[p] = j;
            }
        }
    }
    __syncthreads();
    int m = s_cnt;   // >= 1 (self-loop)

    // ---- P3: stage x values transposed [c][j], pad tail with +huge ----
    float* sv = (float*)s_q4;            // float index: c*(STR*4) + j = c*68 + j
    bool fast = (m <= MAXM);
    if (fast) {
        int mq4 = ((m + 3) >> 2) << 2;
        for (int t = tid; t < mq4 * 64; t += 256) {
            int j = t >> 6, c = t & 63;   // per-wave: one neighbor row, coalesced read
            float v = 3.0e38f;
            if (j < m) v = x[((size_t)(b * NN + s_idx[j])) * NC + c];
            sv[c * 68 + j] = v;
        }
    }
    __syncthreads();

    // ---- P4: rank-selection quantiles. 256 threads = 64 channels x 4 chunks.
    // Tie-correct: value v occupies sorted ranks [rs, rs+re). ----
    float mf = (float)m;
    const float taus[3] = {0.25f, 0.5f, 0.75f};
    const float wts[3]  = {0.25f, 0.5f, 0.25f};
    int tlo[3], thi[3];
    float tfrac[3];
    #pragma unroll
    for (int t = 0; t < 3; ++t) {
        float pos = taus[t] * (mf - 1.0f);   // >= 0 always
        float fl = floorf(pos);
        tlo[t] = (int)fl;
        thi[t] = (int)ceilf(pos);
        tfrac[t] = pos - fl;
    }

    int c = lane;
    if (fast) {
        const float4* basep = s_q4 + c * STR;
        int mq = (m + 3) >> 2;
        for (int j1 = wv; j1 < m; j1 += 4) {
            float v1 = sv[c * 68 + j1];
            int rs = 0, re = 0;
            for (int jq = 0; jq < mq; ++jq) {
                float4 v = basep[jq];
                rs += (v.x < v1) + (v.y < v1) + (v.z < v1) + (v.w < v1);
                re += (v.x == v1) + (v.y == v1) + (v.z == v1) + (v.w == v1);
            }
            #pragma unroll
            for (int t = 0; t < 3; ++t) {
                if (rs <= tlo[t] && tlo[t] < rs + re) s_qv[c * 8 + 2 * t] = v1;
                if (rs <= thi[t] && thi[t] < rs + re) s_qv[c * 8 + 2 * t + 1] = v1;
            }
        }
    } else if (tid < NC) {
        // correctness fallback for m > MAXM (never triggers on bench data)
        const float* xb = x + (size_t)b * NN * NC;
        for (int j1 = 0; j1 < m; ++j1) {
            float v1 = xb[(size_t)s_idx[j1] * NC + c];
            int rs = 0, re = 0;
            for (int j2 = 0; j2 < m; ++j2) {
                float v2 = xb[(size_t)s_idx[j2] * NC + c];
                rs += v2 < v1;
                re += v2 == v1;
            }
            #pragma unroll
            for (int t = 0; t < 3; ++t) {
                if (rs <= tlo[t] && tlo[t] < rs + re) s_qv[c * 8 + 2 * t] = v1;
                if (rs <= thi[t] && thi[t] < rs + re) s_qv[c * 8 + 2 * t + 1] = v1;
            }
        }
    }
    __syncthreads();

    // ---- combine quantiles: out = x + sum wt * lerp(q_lo, q_hi) ----
    if (tid < NC) {
        float agg = 0.0f;
        #pragma unroll
        for (int t = 0; t < 3; ++t) {
            float q = s_qv[tid * 8 + 2 * t] * (1.0f - tfrac[t])
                    + s_qv[tid * 8 + 2 * t + 1] * tfrac[t];
            agg += wts[t] * q;
        }
        s_out[tid] = x[(size_t)row * NC + tid] + agg;
    }
    __syncthreads();

    // ---- GIN MLP: h = relu(out@W1+b1); y = h@W2+b2 ----
    if (tid < NH) {
        int k = tid;
        float acc = b1[k];
        #pragma unroll
        for (int cc = 0; cc < NC; ++cc)
            acc += s_out[cc] * W1[cc * NH + k];
        s_h[k] = acc > 0.0f ? acc : 0.0f;
    }
    __syncthreads();

    if (tid < NCO) {
        int o = tid;
        float acc = b2[o];
        #pragma unroll
        for (int k = 0; k < NH; ++k)
            acc += s_h[k] * W2[k * NCO + o];
        outp[o] = acc;
    }
}

extern "C" void kernel_launch(void* const* d_in, const int* in_sizes, int n_in,
                              void* d_out, int out_size, void* d_ws, size_t ws_size,
                              hipStream_t stream) {
    const float* x   = (const float*)d_in[0];
    const float* adj = (const float*)d_in[1];
    const void* mask = d_in[2];
    const float* W1  = (const float*)d_in[3];
    const float* b1  = (const float*)d_in[4];
    const float* W2  = (const float*)d_in[5];
    const float* b2  = (const float*)d_in[6];
    float* out = (float*)d_out;

    fused_kernel<<<NB * NN, 256, 0, stream>>>(x, adj, mask, W1, b1, W2, b2, out);
}

// Round 3
// 107.527 us; speedup vs baseline: 1.8122x; 1.3990x over previous
//
#include <hip/hip_runtime.h>
#include <stdint.h>

#define NB 4
#define NN 512
#define NC 64
#define NH 128
#define NCO 64
#define MAXM 64          // fast-path cap on valid-neighbor count (realistic max ~55)
#define STR 17           // float4 stride per channel (68 dwords)

// mask dtype decode: int32 (w0==1), float32 (w0==0x3f800000), else packed bytes.
__device__ inline bool read_mask(const void* mp, int idx) {
    const int* ip = (const int*)mp;
    int w0 = ip[0];
    if (w0 == 1) return ip[idx] != 0;
    if (w0 == 0x3f800000) return ((const float*)mp)[idx] != 0.0f;
    return ((const unsigned char*)mp)[idx] != 0;
}

// One wave per row: neighbor census + dilation-removal bitmask (8 u64/row).
// Blocks 0..63 additionally transpose W1 (64x128 -> 128x64) and W2 (128x64 -> 64x128).
__global__ __launch_bounds__(256) void prep_kernel(
        const float* __restrict__ adj, const void* __restrict__ maskp,
        const float* __restrict__ W1, const float* __restrict__ W2,
        uint64_t* __restrict__ rembits, float* __restrict__ W1T,
        float* __restrict__ W2T, int dowt)
{
    int wave = (blockIdx.x * 256 + threadIdx.x) >> 6;
    int lane = threadIdx.x & 63;
    if (wave < NB * NN) {
        int i = wave & (NN - 1);
        const float* arow = adj + (size_t)wave * NN;
        uint64_t ball[8];
        int m = 0;
        #pragma unroll
        for (int k = 0; k < 8; ++k) {
            int j = k * 64 + lane;
            bool f = (j != i) && (arow[j] > 0.0f);
            uint64_t bl = __ballot(f);
            ball[k] = bl;
            m += __popcll(bl);
        }
        int skip = (m > 10) ? ((m + 1) >> 1) : 1;   // ceil(m/2), K_DIL=2
        bool dodil = (skip > 1) && read_mask(maskp, wave);
        int skip2 = skip * 2;
        int prefix = 0;
        #pragma unroll
        for (int k = 0; k < 8; ++k) {
            uint64_t bl = ball[k];
            int rank1 = prefix + __popcll(bl & ((1ull << lane) - 1ull)) + 1;
            bool f = (bl >> lane) & 1ull;
            // (rank % skip)==0  <=>  rank==skip || rank==2*skip   (rank<=m<=2*skip)
            bool rm = f && dodil && (rank1 == skip || rank1 == skip2);
            uint64_t rb = __ballot(rm);
            if (lane == 0) rembits[(size_t)wave * 8 + k] = rb;
            prefix += __popcll(bl);
        }
    }
    if (dowt) {
        int e = blockIdx.x * 256 + threadIdx.x;
        if (e < 8192) {                       // W1T[k][c] = W1[c][k]
            int k = e >> 6, c = e & 63;
            W1T[e] = W1[c * NH + k];
        } else if (e < 16384) {               // W2T[o][k] = W2[k][o]
            int e2 = e - 8192;
            int o = e2 >> 7, k = e2 & 127;
            W2T[e2] = W2[k * NCO + o];
        }
    }
}

// One 256-thread block per row: valid list (parallel bitmask gather) ->
// transposed LDS staging -> float4-quad rank-selection quantiles -> fused MLP.
template<bool USE_WT>
__global__ __launch_bounds__(256) void fused_kernel(
        const float* __restrict__ x,
        const float* __restrict__ adj,
        const void* __restrict__ maskp,
        const float* __restrict__ W1,
        const float* __restrict__ b1,
        const float* __restrict__ W2,
        const float* __restrict__ b2,
        const uint64_t* __restrict__ rembits,
        const float* __restrict__ W1T,
        const float* __restrict__ W2T,
        float* __restrict__ out)
{
    int row = blockIdx.x;                // b*NN + i
    int b = row >> 9, i = row & (NN - 1);
    int tid = threadIdx.x, lane = tid & 63, wv = tid >> 6;
    float* outp = out + (size_t)row * NCO;

    if (!read_mask(maskp, row)) {        // masked row: explicit zeros (out poisoned)
        if (tid < NCO) outp[tid] = 0.0f;
        return;
    }

    __shared__ int s_idx[NN];
    __shared__ int s_cnt;
    __shared__ float4 s_q4[NC * STR];
    __shared__ float s_qv[NC * 8];
    __shared__ float s_out[NC];
    __shared__ float s_h[NH];
    __shared__ float s_hp[2][NH];
    __shared__ float s_part[4][NCO];

    float xval = (tid < NC) ? x[(size_t)row * NC + tid] : 0.0f;  // prefetch
    if (tid == 0) s_cnt = 0;
    __syncthreads();

    // ---- P2: candidate check, fully parallel: adj load + removed-bit gather ----
    const float* arow = adj + (size_t)row * NN;
    const uint64_t* remI = rembits + (size_t)row * 8;
    int ic = i >> 6, ibit = i & 63;
    #pragma unroll
    for (int it = 0; it < 2; ++it) {
        int j = tid + it * 256;
        float a = arow[j];                                        // independent loads
        uint64_t wI = remI[j >> 6];
        uint64_t wJ = rembits[((size_t)(b * NN + j)) * 8 + ic];
        bool valid = (j == i) ||
                     ((a > 0.0f) && !((wI >> (j & 63)) & 1ull)
                                 && !((wJ >> ibit) & 1ull));
        if (valid) {
            int p = atomicAdd(&s_cnt, 1);
            s_idx[p] = j;
        }
    }
    __syncthreads();
    int m = s_cnt;                       // >= 1 (self-loop)

    // ---- P3: stage x transposed [c][j], tail padded with +huge ----
    float* sv = (float*)s_q4;            // float index: c*68 + j
    bool fast = (m <= MAXM);
    int mq = (m + 3) >> 2;
    if (fast) {
        int mq4 = mq << 2;
        for (int t = tid; t < mq4 * 64; t += 256) {
            int j = t >> 6, c = t & 63;  // coalesced x read (64 consecutive c)
            float v = 3.0e38f;
            if (j < m) v = x[((size_t)(b * NN + s_idx[j])) * NC + c];
            sv[c * 68 + j] = v;
        }
    }
    __syncthreads();

    float mf = (float)m;
    const float taus[3] = {0.25f, 0.5f, 0.75f};
    const float wts[3]  = {0.25f, 0.5f, 0.25f};
    int tlo[3], thi[3];
    float tfrac[3];
    #pragma unroll
    for (int t = 0; t < 3; ++t) {
        float pos = taus[t] * (mf - 1.0f);
        float fl = floorf(pos);
        tlo[t] = (int)fl;
        thi[t] = (int)ceilf(pos);
        tfrac[t] = pos - fl;
    }

    // ---- P4: rank selection; each thread owns float4 quads of candidates.
    // Value v occupies sorted ranks [rs, rs+re). Pad (3e38) self-filters: rs>=m. ----
    int c = lane;
    if (fast) {
        const float4* basep = s_q4 + c * STR;
        for (int ch = wv; ch < mq; ch += 4) {
            float4 q1 = basep[ch];
            int rs0 = 0, rs1 = 0, rs2 = 0, rs3 = 0;
            int re0 = 0, re1 = 0, re2 = 0, re3 = 0;
            for (int jq = 0; jq < mq; ++jq) {
                float4 v = basep[jq];
                rs0 += (v.x < q1.x) + (v.y < q1.x) + (v.z < q1.x) + (v.w < q1.x);
                re0 += (v.x == q1.x) + (v.y == q1.x) + (v.z == q1.x) + (v.w == q1.x);
                rs1 += (v.x < q1.y) + (v.y < q1.y) + (v.z < q1.y) + (v.w < q1.y);
                re1 += (v.x == q1.y) + (v.y == q1.y) + (v.z == q1.y) + (v.w == q1.y);
                rs2 += (v.x < q1.z) + (v.y < q1.z) + (v.z < q1.z) + (v.w < q1.z);
                re2 += (v.x == q1.z) + (v.y == q1.z) + (v.z == q1.z) + (v.w == q1.z);
                rs3 += (v.x < q1.w) + (v.y < q1.w) + (v.z < q1.w) + (v.w < q1.w);
                re3 += (v.x == q1.w) + (v.y == q1.w) + (v.z == q1.w) + (v.w == q1.w);
            }
            float qe[4] = {q1.x, q1.y, q1.z, q1.w};
            int rsa[4] = {rs0, rs1, rs2, rs3};
            int rea[4] = {re0, re1, re2, re3};
            #pragma unroll
            for (int q = 0; q < 4; ++q) {
                #pragma unroll
                for (int t = 0; t < 3; ++t) {
                    if (rsa[q] <= tlo[t] && tlo[t] < rsa[q] + rea[q])
                        s_qv[c * 8 + 2 * t] = qe[q];
                    if (rsa[q] <= thi[t] && thi[t] < rsa[q] + rea[q])
                        s_qv[c * 8 + 2 * t + 1] = qe[q];
                }
            }
        }
    } else if (tid < NC) {
        // correctness fallback for m > MAXM (doesn't trigger on bench data)
        const float* xb = x + (size_t)b * NN * NC;
        for (int j1 = 0; j1 < m; ++j1) {
            float v1 = xb[(size_t)s_idx[j1] * NC + c];
            int rs = 0, re = 0;
            for (int j2 = 0; j2 < m; ++j2) {
                float v2 = xb[(size_t)s_idx[j2] * NC + c];
                rs += v2 < v1;
                re += v2 == v1;
            }
            #pragma unroll
            for (int t = 0; t < 3; ++t) {
                if (rs <= tlo[t] && tlo[t] < rs + re) s_qv[c * 8 + 2 * t] = v1;
                if (rs <= thi[t] && thi[t] < rs + re) s_qv[c * 8 + 2 * t + 1] = v1;
            }
        }
    }
    __syncthreads();

    // ---- combine: out = x + sum wt * lerp(q_lo, q_hi) ----
    if (tid < NC) {
        float agg = 0.0f;
        #pragma unroll
        for (int t = 0; t < 3; ++t) {
            float q = s_qv[tid * 8 + 2 * t] * (1.0f - tfrac[t])
                    + s_qv[tid * 8 + 2 * t + 1] * tfrac[t];
            agg += wts[t] * q;
        }
        s_out[tid] = xval + agg;
    }
    __syncthreads();

    // ---- MLP phase 1: h = relu(out@W1+b1); 256 threads = 128 k x 2 cc-groups ----
    {
        int k = tid & 127, g = tid >> 7;
        float acc = 0.0f;
        if (USE_WT) {
            const float4* w = (const float4*)(W1T + k * 64 + g * 32);
            #pragma unroll
            for (int q = 0; q < 8; ++q) {
                float4 wq = w[q];
                int cc = g * 32 + q * 4;
                acc += wq.x * s_out[cc] + wq.y * s_out[cc + 1]
                     + wq.z * s_out[cc + 2] + wq.w * s_out[cc + 3];
            }
        } else {
            for (int cc = g * 32; cc < g * 32 + 32; ++cc)
                acc += s_out[cc] * W1[cc * NH + k];
        }
        s_hp[g][k] = acc;
    }
    __syncthreads();
    if (tid < NH) {
        float acc = s_hp[0][tid] + s_hp[1][tid] + b1[tid];
        s_h[tid] = acc > 0.0f ? acc : 0.0f;
    }
    __syncthreads();

    // ---- MLP phase 2: y = h@W2+b2; 256 threads = 64 o x 4 k-groups ----
    {
        int o = tid & 63, g = tid >> 6;
        float acc = 0.0f;
        if (USE_WT) {
            const float4* w = (const float4*)(W2T + o * 128 + g * 32);
            #pragma unroll
            for (int q = 0; q < 8; ++q) {
                float4 wq = w[q];
                int k = g * 32 + q * 4;
                acc += wq.x * s_h[k] + wq.y * s_h[k + 1]
                     + wq.z * s_h[k + 2] + wq.w * s_h[k + 3];
            }
        } else {
            for (int k = g * 32; k < g * 32 + 32; ++k)
                acc += s_h[k] * W2[k * NCO + o];
        }
        s_part[g][o] = acc;
    }
    __syncthreads();
    if (tid < NCO)
        outp[tid] = s_part[0][tid] + s_part[1][tid] + s_part[2][tid]
                  + s_part[3][tid] + b2[tid];
}

extern "C" void kernel_launch(void* const* d_in, const int* in_sizes, int n_in,
                              void* d_out, int out_size, void* d_ws, size_t ws_size,
                              hipStream_t stream) {
    const float* x   = (const float*)d_in[0];
    const float* adj = (const float*)d_in[1];
    const void* mask = d_in[2];
    const float* W1  = (const float*)d_in[3];
    const float* b1  = (const float*)d_in[4];
    const float* W2  = (const float*)d_in[5];
    const float* b2  = (const float*)d_in[6];
    float* out = (float*)d_out;

    uint64_t* rembits = (uint64_t*)d_ws;                 // 128 KB
    float* W1T = (float*)((char*)d_ws + 131072);         // 32 KB
    float* W2T = W1T + 8192;                             // 32 KB
    int dowt = (ws_size >= 196608) ? 1 : 0;

    prep_kernel<<<512, 256, 0, stream>>>(adj, mask, W1, W2, rembits, W1T, W2T, dowt);
    if (dowt)
        fused_kernel<true><<<NB * NN, 256, 0, stream>>>(
            x, adj, mask, W1, b1, W2, b2, rembits, W1T, W2T, out);
    else
        fused_kernel<false><<<NB * NN, 256, 0, stream>>>(
            x, adj, mask, W1, b1, W2, b2, rembits, W1T, W2T, out);
}

// Round 4
// 103.494 us; speedup vs baseline: 1.8828x; 1.0390x over previous
//
#include <hip/hip_runtime.h>
#include <stdint.h>

#define NB 4
#define NN 512
#define NC 64
#define NH 128
#define NCO 64
#define MAXM 64          // fast-path cap on valid count (realistic max ~55)
#define MAXQ 16          // MAXM/4 float4 quads per channel

// mask dtype decode: int32 (w0==1), float32 (w0==0x3f800000), else packed bytes.
__device__ inline bool read_mask(const void* mp, int idx) {
    const int* ip = (const int*)mp;
    int w0 = ip[0];
    if (w0 == 1) return ip[idx] != 0;
    if (w0 == 0x3f800000) return ((const float*)mp)[idx] != 0.0f;
    return ((const unsigned char*)mp)[idx] != 0;
}

// One wave per row: neighbor census -> validbits = neighbors surviving row i's
// own dilation removal (self excluded). Symmetric removal then reduces to
// valid(i,j) = vb_i[j] && vb_j[i]. Blocks 0..63 also transpose W1/W2.
__global__ __launch_bounds__(256) void prep_kernel(
        const float* __restrict__ adj, const void* __restrict__ maskp,
        const float* __restrict__ W1, const float* __restrict__ W2,
        uint64_t* __restrict__ validbits, float* __restrict__ W1T,
        float* __restrict__ W2T, int dowt)
{
    int wave = (blockIdx.x * 256 + threadIdx.x) >> 6;
    int lane = threadIdx.x & 63;
    if (wave < NB * NN) {
        int i = wave & (NN - 1);
        const float* arow = adj + (size_t)wave * NN;
        uint64_t ball[8];
        int m = 0;
        #pragma unroll
        for (int k = 0; k < 8; ++k) {
            int j = k * 64 + lane;
            bool f = (j != i) && (arow[j] > 0.0f);
            uint64_t bl = __ballot(f);
            ball[k] = bl;
            m += __popcll(bl);
        }
        int skip = (m > 10) ? ((m + 1) >> 1) : 1;   // ceil(m/2), K_DIL=2
        bool dodil = (skip > 1) && read_mask(maskp, wave);
        int skip2 = skip * 2;
        int prefix = 0;
        #pragma unroll
        for (int k = 0; k < 8; ++k) {
            uint64_t bl = ball[k];
            int rank1 = prefix + __popcll(bl & ((1ull << lane) - 1ull)) + 1;
            bool f = (bl >> lane) & 1ull;
            // (rank % skip)==0 <=> rank==skip || rank==2*skip  (rank <= m <= 2*skip)
            bool keep = f && !(dodil && (rank1 == skip || rank1 == skip2));
            uint64_t vb = __ballot(keep);
            if (lane == 0) validbits[(size_t)wave * 8 + k] = vb;
            prefix += __popcll(bl);
        }
    }
    if (dowt) {
        int e = blockIdx.x * 256 + threadIdx.x;
        if (e < 8192) {                       // W1T[k][c] = W1[c][k]
            int k = e >> 6, c = e & 63;
            W1T[e] = W1[c * NH + k];
        } else if (e < 16384) {               // W2T[o][k] = W2[k][o]
            int e2 = e - 8192;
            int o = e2 >> 7, k = e2 & 127;
            W2T[e2] = W2[k * NCO + o];
        }
    }
}

// One 256-thread block per row. LDS = 19.5 KB -> 8 blocks/CU (whole grid
// resident in one round). MLP scratch overlays the staging buffer post-P4.
template<bool USE_WT>
__global__ __launch_bounds__(256, 8) void fused_kernel(
        const float* __restrict__ x,
        const void* __restrict__ maskp,
        const float* __restrict__ W1,
        const float* __restrict__ b1,
        const float* __restrict__ W2,
        const float* __restrict__ b2,
        const uint64_t* __restrict__ validbits,
        const float* __restrict__ W1T,
        const float* __restrict__ W2T,
        float* __restrict__ out)
{
    int row = blockIdx.x;                // b*NN + i
    int b = row >> 9, i = row & (NN - 1);
    int tid = threadIdx.x, lane = tid & 63, wv = tid >> 6;
    float* outp = out + (size_t)row * NCO;

    if (!read_mask(maskp, row)) {        // masked row: explicit zeros (out poisoned)
        if (tid < NCO) outp[tid] = 0.0f;
        return;
    }

    __shared__ float4 s_q4[NC * MAXQ];   // 16 KB staging; reused as MLP scratch
    __shared__ uint16_t s_idx[NN];       // valid list (unordered); 1 KB
    __shared__ float s_qv[NC * 8];       // quantile candidate slots; 2 KB
    __shared__ uint64_t s_vb[8];         // row i's validbits
    __shared__ int s_cnt;

    float xval = (tid < NC) ? x[(size_t)row * NC + tid] : 0.0f;  // prefetch
    if (tid < 8) s_vb[tid] = validbits[(size_t)row * 8 + tid];
    if (tid == 0) { s_cnt = 1; s_idx[0] = (uint16_t)i; }         // self at slot 0
    __syncthreads();

    // ---- P2: valid(i,j) = vb_i[j] && vb_j[i]; gather only for real neighbors ----
    int ic = i >> 6;
    uint64_t imask = 1ull << (i & 63);
    #pragma unroll
    for (int it = 0; it < 2; ++it) {
        int j = tid + it * 256;
        if ((s_vb[j >> 6] >> (j & 63)) & 1ull) {
            uint64_t wJ = validbits[((size_t)(b * NN + j)) * 8 + ic];
            if (wJ & imask) {
                int p = atomicAdd(&s_cnt, 1);
                s_idx[p] = (uint16_t)j;
            }
        }
    }
    __syncthreads();
    int m = s_cnt;                       // >= 1 (self-loop)

    // ---- P3: stage x transposed [c][quad], XOR-16 swizzled, tail = +huge ----
    bool fast = (m <= MAXM);
    int mq = (m + 3) >> 2;
    float* sv = (float*)s_q4;
    if (fast) {
        int mq4 = mq << 2;
        for (int j = wv; j < mq4; j += 4) {          // wave wv owns neighbor j
            float v = 3.0e38f;
            if (j < m) v = x[((size_t)(b * NN + s_idx[j])) * NC + lane];
            int slot = (j >> 2) ^ (lane & 15);
            sv[lane * 64 + slot * 4 + (j & 3)] = v;
        }
    }
    __syncthreads();

    // ---- quantile positions (torch 'linear') ----
    float mf = (float)m;
    const float taus[3] = {0.25f, 0.5f, 0.75f};
    const float wts[3]  = {0.25f, 0.5f, 0.25f};
    int tlo[3], thi[3];
    float tfrac[3];
    #pragma unroll
    for (int t = 0; t < 3; ++t) {
        float pos = taus[t] * (mf - 1.0f);
        float fl = floorf(pos);
        tlo[t] = (int)fl;
        thi[t] = (int)ceilf(pos);
        tfrac[t] = pos - fl;
    }

    // ---- P4: rank selection; value v occupies sorted ranks [rs, rs+re).
    // Padding (3e38) self-filters (rs >= m > thi). ----
    if (fast) {
        const float4* basep = s_q4 + lane * MAXQ;
        int sw = lane & 15;
        for (int ch = wv; ch < mq; ch += 4) {
            float4 q1 = basep[ch ^ sw];
            int rs0 = 0, rs1 = 0, rs2 = 0, rs3 = 0;
            int re0 = 0, re1 = 0, re2 = 0, re3 = 0;
            for (int jq = 0; jq < mq; ++jq) {
                float4 v = basep[jq ^ sw];
                rs0 += (v.x < q1.x) + (v.y < q1.x) + (v.z < q1.x) + (v.w < q1.x);
                re0 += (v.x == q1.x) + (v.y == q1.x) + (v.z == q1.x) + (v.w == q1.x);
                rs1 += (v.x < q1.y) + (v.y < q1.y) + (v.z < q1.y) + (v.w < q1.y);
                re1 += (v.x == q1.y) + (v.y == q1.y) + (v.z == q1.y) + (v.w == q1.y);
                rs2 += (v.x < q1.z) + (v.y < q1.z) + (v.z < q1.z) + (v.w < q1.z);
                re2 += (v.x == q1.z) + (v.y == q1.z) + (v.z == q1.z) + (v.w == q1.z);
                rs3 += (v.x < q1.w) + (v.y < q1.w) + (v.z < q1.w) + (v.w < q1.w);
                re3 += (v.x == q1.w) + (v.y == q1.w) + (v.z == q1.w) + (v.w == q1.w);
            }
            float qe[4] = {q1.x, q1.y, q1.z, q1.w};
            int rsa[4] = {rs0, rs1, rs2, rs3};
            int rea[4] = {re0, re1, re2, re3};
            #pragma unroll
            for (int q = 0; q < 4; ++q) {
                #pragma unroll
                for (int t = 0; t < 3; ++t) {
                    if (rsa[q] <= tlo[t] && tlo[t] < rsa[q] + rea[q])
                        s_qv[lane * 8 + 2 * t] = qe[q];
                    if (rsa[q] <= thi[t] && thi[t] < rsa[q] + rea[q])
                        s_qv[lane * 8 + 2 * t + 1] = qe[q];
                }
            }
        }
    } else if (tid < NC) {
        // correctness fallback for m > MAXM (doesn't trigger on bench data)
        const float* xb = x + (size_t)b * NN * NC;
        int c = tid;
        for (int j1 = 0; j1 < m; ++j1) {
            float v1 = xb[(size_t)s_idx[j1] * NC + c];
            int rs = 0, re = 0;
            for (int j2 = 0; j2 < m; ++j2) {
                float v2 = xb[(size_t)s_idx[j2] * NC + c];
                rs += v2 < v1;
                re += v2 == v1;
            }
            #pragma unroll
            for (int t = 0; t < 3; ++t) {
                if (rs <= tlo[t] && tlo[t] < rs + re) s_qv[c * 8 + 2 * t] = v1;
                if (rs <= thi[t] && thi[t] < rs + re) s_qv[c * 8 + 2 * t + 1] = v1;
            }
        }
    }
    __syncthreads();

    // ---- MLP scratch overlays the (now dead) staging buffer ----
    float* s_mlp  = (float*)s_q4;
    float* s_out  = s_mlp;               // [0,64)
    float* s_h    = s_mlp + 64;          // [64,192)
    float* s_hp   = s_mlp + 256;         // [256,512)
    float* s_part = s_mlp + 512;         // [512,768)

    if (tid < NC) {                      // out = x + sum wt * lerp(q_lo, q_hi)
        float agg = 0.0f;
        #pragma unroll
        for (int t = 0; t < 3; ++t) {
            float q = s_qv[tid * 8 + 2 * t] * (1.0f - tfrac[t])
                    + s_qv[tid * 8 + 2 * t + 1] * tfrac[t];
            agg += wts[t] * q;
        }
        s_out[tid] = xval + agg;
    }
    __syncthreads();

    // ---- MLP1: 256 threads = 128 k x 2 cc-halves ----
    {
        int k = tid & 127, g = tid >> 7;
        float acc = 0.0f;
        if (USE_WT) {
            const float4* w = (const float4*)(W1T + k * 64 + g * 32);
            #pragma unroll
            for (int q = 0; q < 8; ++q) {
                float4 wq = w[q];
                int cc = g * 32 + q * 4;
                acc += wq.x * s_out[cc] + wq.y * s_out[cc + 1]
                     + wq.z * s_out[cc + 2] + wq.w * s_out[cc + 3];
            }
        } else {
            for (int cc = g * 32; cc < g * 32 + 32; ++cc)
                acc += s_out[cc] * W1[cc * NH + k];
        }
        s_hp[g * NH + k] = acc;
    }
    __syncthreads();
    if (tid < NH) {
        float a = s_hp[tid] + s_hp[NH + tid] + b1[tid];
        s_h[tid] = a > 0.0f ? a : 0.0f;
    }
    __syncthreads();

    // ---- MLP2: 256 threads = 64 o x 4 k-quarters ----
    {
        int o = tid & 63, g = tid >> 6;
        float acc = 0.0f;
        if (USE_WT) {
            const float4* w = (const float4*)(W2T + o * 128 + g * 32);
            #pragma unroll
            for (int q = 0; q < 8; ++q) {
                float4 wq = w[q];
                int k = g * 32 + q * 4;
                acc += wq.x * s_h[k] + wq.y * s_h[k + 1]
                     + wq.z * s_h[k + 2] + wq.w * s_h[k + 3];
            }
        } else {
            for (int k = g * 32; k < g * 32 + 32; ++k)
                acc += s_h[k] * W2[k * NCO + o];
        }
        s_part[g * NCO + o] = acc;
    }
    __syncthreads();
    if (tid < NCO)
        outp[tid] = s_part[tid] + s_part[64 + tid] + s_part[128 + tid]
                  + s_part[192 + tid] + b2[tid];
}

extern "C" void kernel_launch(void* const* d_in, const int* in_sizes, int n_in,
                              void* d_out, int out_size, void* d_ws, size_t ws_size,
                              hipStream_t stream) {
    const float* x   = (const float*)d_in[0];
    const float* adj = (const float*)d_in[1];
    const void* mask = d_in[2];
    const float* W1  = (const float*)d_in[3];
    const float* b1  = (const float*)d_in[4];
    const float* W2  = (const float*)d_in[5];
    const float* b2  = (const float*)d_in[6];
    float* out = (float*)d_out;

    uint64_t* validbits = (uint64_t*)d_ws;               // 128 KB
    float* W1T = (float*)((char*)d_ws + 131072);         // 32 KB
    float* W2T = W1T + 8192;                             // 32 KB
    int dowt = (ws_size >= 196608) ? 1 : 0;

    prep_kernel<<<512, 256, 0, stream>>>(adj, mask, W1, W2, validbits, W1T, W2T, dowt);
    if (dowt)
        fused_kernel<true><<<NB * NN, 256, 0, stream>>>(
            x, mask, W1, b1, W2, b2, validbits, W1T, W2T, out);
    else
        fused_kernel<false><<<NB * NN, 256, 0, stream>>>(
            x, mask, W1, b1, W2, b2, validbits, W1T, W2T, out);
}